// Round 16
// baseline (567.261 us; speedup 1.0000x reference)
//
#include <hip/hip_runtime.h>
#include <math.h>

#define D_DIM 512
#define RANK_ 128
#define NPTS 1024

// ---------------- helpers ----------------
__device__ __forceinline__ float blockReduceSum128(float v, float* sbuf) {
  #pragma unroll
  for (int off = 32; off > 0; off >>= 1) v += __shfl_down(v, off);
  int tid = threadIdx.x;
  if ((tid & 63) == 0) sbuf[tid >> 6] = v;
  __syncthreads();
  float r = sbuf[0] + sbuf[1];
  __syncthreads();
  return r;
}

// ---------------- HF = H @ F ; c[i] = H_row_i . mu ----------------
__global__ void k_hf(const float* __restrict__ H, const float* __restrict__ F,
                     const float* __restrict__ mu, float* __restrict__ HF,
                     float* __restrict__ cvec) {
  __shared__ float hrow[D_DIM];
  __shared__ float sbuf[2];
  int i = blockIdx.x;        // 0..511
  int tid = threadIdx.x;     // 128 threads
  for (int d = tid; d < D_DIM; d += 128) hrow[d] = H[i * D_DIM + d];
  __syncthreads();
  float part = 0.f;
  for (int d = tid; d < D_DIM; d += 128) part += hrow[d] * mu[d];
  float ci = blockReduceSum128(part, sbuf);
  if (tid == 0) cvec[i] = ci;
  float acc = 0.f;
  for (int d = 0; d < D_DIM; ++d) acc += hrow[d] * F[d * RANK_ + tid];
  HF[i * RANK_ + tid] = acc;
}

// ---------------- B0 = HF^T @ HF ----------------
__global__ void k_b0(const float* __restrict__ HF, float* __restrict__ B0) {
  __shared__ float col[D_DIM];
  int r1 = blockIdx.x;       // 0..127
  int tid = threadIdx.x;     // 128
  for (int i = tid; i < D_DIM; i += 128) col[i] = HF[i * RANK_ + r1];
  __syncthreads();
  float acc = 0.f;
  for (int i = 0; i < D_DIM; ++i) acc += col[i] * HF[i * RANK_ + tid];
  B0[r1 * RANK_ + tid] = acc;
}

// ---------------- R1[n][i] = sum_d x[n][d]*H[i][d] - c[i] ----------------
__global__ void k_r1(const float* __restrict__ x, const float* __restrict__ H,
                     const float* __restrict__ cvec, float* __restrict__ R1) {
  __shared__ float xs[32][33];
  __shared__ float hs[64][33];
  int tid = threadIdx.x;
  int n0 = blockIdx.x * 32, i0 = blockIdx.y * 64;
  int tx = tid & 15, ty = tid >> 4;
  float acc[2][4] = {{0.f,0.f,0.f,0.f},{0.f,0.f,0.f,0.f}};
  for (int k0 = 0; k0 < D_DIM; k0 += 32) {
    {
      int idx = tid;
      int r = idx >> 3, c4 = (idx & 7) << 2;
      float4 v = *(const float4*)&x[(n0 + r) * D_DIM + k0 + c4];
      xs[r][c4+0]=v.x; xs[r][c4+1]=v.y; xs[r][c4+2]=v.z; xs[r][c4+3]=v.w;
    }
    #pragma unroll
    for (int l = 0; l < 2; ++l) {
      int idx = tid + l * 256;
      int r = idx >> 3, c4 = (idx & 7) << 2;
      float4 v = *(const float4*)&H[(i0 + r) * D_DIM + k0 + c4];
      hs[r][c4+0]=v.x; hs[r][c4+1]=v.y; hs[r][c4+2]=v.z; hs[r][c4+3]=v.w;
    }
    __syncthreads();
    #pragma unroll
    for (int k = 0; k < 32; ++k) {
      float a0 = xs[ty*2+0][k], a1 = xs[ty*2+1][k];
      float b0 = hs[tx*4+0][k], b1 = hs[tx*4+1][k];
      float b2 = hs[tx*4+2][k], b3 = hs[tx*4+3][k];
      acc[0][0] = fmaf(a0,b0,acc[0][0]); acc[0][1] = fmaf(a0,b1,acc[0][1]);
      acc[0][2] = fmaf(a0,b2,acc[0][2]); acc[0][3] = fmaf(a0,b3,acc[0][3]);
      acc[1][0] = fmaf(a1,b0,acc[1][0]); acc[1][1] = fmaf(a1,b1,acc[1][1]);
      acc[1][2] = fmaf(a1,b2,acc[1][2]); acc[1][3] = fmaf(a1,b3,acc[1][3]);
    }
    __syncthreads();
  }
  #pragma unroll
  for (int ii = 0; ii < 2; ++ii)
    #pragma unroll
    for (int j = 0; j < 4; ++j)
      R1[(n0 + ty*2 + ii) * D_DIM + i0 + tx*4 + j] = acc[ii][j] - cvec[i0 + tx*4 + j];
}

// ---------------- PT = R1 @ HF ; q1[n] = |R1 row|^2 ----------------
__global__ void k_pt(const float* __restrict__ R1, const float* __restrict__ HF,
                     float* __restrict__ PT, float* __restrict__ q1) {
  __shared__ float row[D_DIM];
  __shared__ float sbuf[2];
  int n = blockIdx.x, tid = threadIdx.x;  // 128
  float part = 0.f;
  for (int i = tid; i < D_DIM; i += 128) {
    float v = R1[n * D_DIM + i];
    row[i] = v;
    part += v * v;
  }
  float q = blockReduceSum128(part, sbuf);
  if (tid == 0) q1[n] = q;
  float acc = 0.f;
  for (int i = 0; i < D_DIM; ++i) acc += row[i] * HF[i * RANK_ + tid];
  PT[n * RANK_ + tid] = acc;
}

// ---------------- Householder tridiagonalization (r8 structure, green-proven
// r13/r14) + FUSED bisection tail. dsh/esh mirror dg/eg in LDS; the trisection
// code is bit-identical to r14's k_bisect, plus a positivity clamp on lamb
// (B0 is PD so exact lambda>0; clamp closes the log(neg)/den<0 NaN path). ----
__global__ __launch_bounds__(512, 1) void k_tridiag(const float* __restrict__ B0,
                                                    float* __restrict__ dg,
                                                    float* __restrict__ eg,
                                                    float* __restrict__ vh,
                                                    float* __restrict__ betag,
                                                    float* __restrict__ lamb) {
  __shared__ __align__(16) float As[128][132];
  __shared__ __align__(16) float vbuf[128];
  __shared__ __align__(16) float wraw[128];
  __shared__ float red1[2];
  __shared__ float red2[8];
  __shared__ float dsh[128], esh[128], besb[128];
  __shared__ float gred[4];
  int tid = threadIdx.x;     // 512
  int lane = tid & 63, wv = tid >> 6;
  int slot = tid >> 2, sid = tid & 3;
  for (int idx = tid; idx < 128 * 128; idx += 512) {
    int i = idx >> 7, j = idx & 127;
    As[i][j] = B0[idx];
  }
  __syncthreads();

  for (int k = 0; k < 126; ++k) {
    int base = k + 1;
    int cb0 = base & ~3;           // f4-aligned active column window [cb0,128)
    int nf4 = (128 - cb0) >> 2;
    int bc = base & 3;             // base component within first f4
    // ---- phase 1: raw x -> vbuf (zeros below base), partial sigma^2 ----
    float xv = 0.f, px = 0.f;
    if (tid < 128) {
      xv = (tid >= base) ? As[tid][k] : 0.f;
      vbuf[tid] = xv;
      px = xv * xv;
    }
    #pragma unroll
    for (int o = 32; o > 0; o >>= 1) px += __shfl_down(px, o);
    if (tid < 128 && lane == 0) red1[wv] = px;
    __syncthreads();                                     // barrier 1
    // ---- redundant scalar Householder params (all 512 threads) ----
    float s2 = red1[0] + red1[1];
    float x1 = vbuf[base];       // LDS broadcast (raw)
    float beta = 0.f, e_k = 0.f, v1 = 0.f;
    if (s2 > 0.f) {
      float sg = sqrtf(s2);
      float sgn = (x1 >= 0.f) ? 1.f : -1.f;
      v1 = x1 + sgn * sg;
      float vtv = s2 - x1 * x1 + v1 * v1;
      beta = 2.f / vtv;
      e_k = -sgn * sg;
    }
    if (tid == 0) {
      float dkk = As[k][k];
      dg[k] = dkk; eg[k] = e_k; betag[k] = beta;
      dsh[k] = dkk; esh[k] = e_k;
    }
    if (tid < 128) vh[k * 128 + tid] = (tid == base) ? v1 : xv;
    // zero stale wraw entries in [cb0, base): read by phase 4's f4 loads
    if (tid < 3 && cb0 + tid < base) wraw[cb0 + tid] = 0.f;
    // ---- phase 2: rowdot with patched-v f4 loads; fused S reduce ----
    int j = base + slot;
    const int rowbase = cb0;
    float sp = 0.f;
    {
      float part = 0.f;
      if (j < 128) {
        const float* arow = &As[j][0];
        for (int t4 = sid; t4 < nf4; t4 += 4) {
          float4 a = *(const float4*)&arow[rowbase + 4 * t4];
          float4 v = *(const float4*)&vbuf[rowbase + 4 * t4];
          if (t4 == 0) {           // f4 containing base: substitute v1
            v.x = (bc == 0) ? v1 : v.x;
            v.y = (bc == 1) ? v1 : v.y;
            v.z = (bc == 2) ? v1 : v.z;
            v.w = (bc == 3) ? v1 : v.w;
          }
          part += a.x * v.x + a.y * v.y + a.z * v.z + a.w * v.w;
        }
      }
      part += __shfl_xor(part, 1);
      part += __shfl_xor(part, 2);
      if (j < 128 && sid == 0) {
        wraw[j] = part;
        float vj = (j == base) ? v1 : vbuf[j];
        sp = vj * part;
      }
    }
    #pragma unroll
    for (int o = 32; o > 0; o >>= 1) sp += __shfl_down(sp, o);
    if (lane == 0) red2[wv] = sp;
    __syncthreads();                                     // barrier 2
    // ---- phase 4 (merged w/ 3): A -= v*w^T + w*v^T, w computed on the fly --
    float S = red2[0] + red2[1] + red2[2] + red2[3]
            + red2[4] + red2[5] + red2[6] + red2[7];
    float coef = 0.5f * beta * beta * S;
    if (j < 128) {
      float vj = (j == base) ? v1 : vbuf[j];
      float wj = beta * wraw[j] - coef * vj;
      float* arow = &As[j][0];
      for (int t4 = sid; t4 < nf4; t4 += 4) {
        float4* ap = (float4*)&arow[rowbase + 4 * t4];
        float4 v = *(const float4*)&vbuf[rowbase + 4 * t4];
        float4 wr = *(const float4*)&wraw[rowbase + 4 * t4];
        if (t4 == 0) {
          v.x = (bc == 0) ? v1 : v.x;
          v.y = (bc == 1) ? v1 : v.y;
          v.z = (bc == 2) ? v1 : v.z;
          v.w = (bc == 3) ? v1 : v.w;
        }
        float4 w4;
        w4.x = beta * wr.x - coef * v.x;
        w4.y = beta * wr.y - coef * v.y;
        w4.z = beta * wr.z - coef * v.z;
        w4.w = beta * wr.w - coef * v.w;
        float4 a = *ap;
        a.x -= vj * w4.x + wj * v.x;
        a.y -= vj * w4.y + wj * v.y;
        a.z -= vj * w4.z + wj * v.z;
        a.w -= vj * w4.w + wj * v.w;
        *ap = a;
      }
    }
    __syncthreads();                                     // barrier 3
  }
  if (tid == 0) {
    float d126 = As[126][126], d127 = As[127][127], e126 = As[127][126];
    dg[126] = d126; dg[127] = d127;
    eg[126] = e126; eg[127] = 0.f;
    betag[126] = 0.f; betag[127] = 0.f;
    dsh[126] = d126; dsh[127] = d127;
    esh[126] = e126; esh[127] = 0.f;
  }
  __syncthreads();

  // ================= fused bisection (pdv=vbuf, pev=wraw) ====================
  float* pdv = vbuf;
  float* pev = wraw;
  float dvv = 0.f;
  if (tid < 128) {
    dvv = dsh[tid];
    float ev = (tid < 127) ? esh[tid] : 0.f;
    pdv[tid] = dvv;
    besb[tid] = fabsf(ev);
  }
  __syncthreads();
  if (tid < 128) {
    float em1 = (tid > 0) ? besb[tid - 1] : 0.f;
    pev[tid] = em1 * em1;                  // pe[k] = e_{k-1}^2, pe[0]=0
    float rad = em1 + besb[tid];
    float lo_k = dvv - rad, hi_k = dvv + rad;
    #pragma unroll
    for (int o = 32; o > 0; o >>= 1) {
      lo_k = fminf(lo_k, __shfl_down(lo_k, o));
      hi_k = fmaxf(hi_k, __shfl_down(hi_k, o));
    }
    if (lane == 0) { gred[wv * 2] = lo_k; gred[wv * 2 + 1] = hi_k; }
  }
  __syncthreads();
  if (tid < 128) {
    float gl = fminf(gred[0], gred[2]), gu = fmaxf(gred[1], gred[3]);
    float span = gu - gl;
    gl -= 0.01f * span + 1e-3f;
    gu += 0.01f * span + 1e-3f;
    float lo = gl, hi = gu;
    const float PIVMIN = 1e-20f;
    for (int it = 0; it < 16; ++it) {
      float w3 = (hi - lo) * (1.f / 3.f);
      float m1 = lo + w3, m2 = hi - w3;
      int c1 = 0, c2 = 0;
      float q1 = 1.f, q2 = 1.f;
      #pragma unroll 1
      for (int kq = 0; kq < 32; ++kq) {
        float4 pd4 = *(const float4*)&pdv[kq * 4];
        float4 pe4 = *(const float4*)&pev[kq * 4];
        #pragma unroll
        for (int u = 0; u < 4; ++u) {
          float dk = (u == 0) ? pd4.x : (u == 1) ? pd4.y : (u == 2) ? pd4.z : pd4.w;
          float ee = (u == 0) ? pe4.x : (u == 1) ? pe4.y : (u == 2) ? pe4.z : pe4.w;
          if (fabsf(q1) < PIVMIN) q1 = -PIVMIN;
          if (fabsf(q2) < PIVMIN) q2 = -PIVMIN;
          q1 = (dk - m1) - ee * __builtin_amdgcn_rcpf(q1);
          q2 = (dk - m2) - ee * __builtin_amdgcn_rcpf(q2);
          c1 += (q1 < 0.f); c2 += (q2 < 0.f);
        }
      }
      if (c1 > tid)       hi = m1;
      else if (c2 > tid) { lo = m1; hi = m2; }
      else                lo = m2;
    }
    // positivity clamp: B0 is PD so exact lambda > 0; guarantees den=1+b*lam>1
    // downstream for any bisection outcome.
    lamb[tid] = fmaxf(0.5f * (lo + hi), 1e-6f);
  }
}

// ---------------- inverse iteration: branchless pivoting, pipelined ---------
__global__ __launch_bounds__(64) void k_invit(const float* __restrict__ dg,
                                              const float* __restrict__ eg,
                                              const float* __restrict__ lamb,
                                              float* __restrict__ Vtri) {
  __shared__ float al[128], bu[128], du[128], ml[128], es[128], y[128];
  __shared__ float esp[128], alp[128], ral[128];
  __shared__ int sw[128];
  int b = blockIdx.x, tid = threadIdx.x;  // 64
  float lam = lamb[b];
  for (int t = tid; t < 128; t += 64) {
    float av = dg[t] - lam;
    al[t] = av;
    float e_ = (t < 127) ? eg[t] : 0.f;
    es[t] = e_;
    unsigned int h = (unsigned int)(t * 2654435761u) ^ (unsigned int)(b * 0x9E3779B9u);
    h ^= h >> 16; h *= 0x85EBCA6Bu; h ^= h >> 13;
    y[t] = 0.5f + (float)(h & 0xFFFF) * (1.0f / 65536.0f);
  }
  __syncthreads();
  for (int t = tid; t < 128; t += 64) {
    esp[t] = (t < 127) ? es[t + 1] : 0.f;
    alp[t] = (t < 127) ? al[t + 1] : 0.f;
  }
  __syncthreads();
  if (tid == 0) {
    const float PIVMIN = 1e-20f;
    float a_cur = al[0];
    float b_cur = es[0];
    #pragma unroll 4
    for (int k = 0; k < 127; ++k) {
      float gk = es[k], e_nx = esp[k], a_nx = alp[k];
      bool cond = fabsf(a_cur) >= fabsf(gk);
      float ac_cl = a_cur;
      if (fabsf(ac_cl) < PIVMIN) ac_cl = (ac_cl >= 0.f) ? PIVMIN : -PIVMIN;
      float m_a = gk * __builtin_amdgcn_rcpf(ac_cl);
      float m_b = a_cur * __builtin_amdgcn_rcpf(gk);
      float m = cond ? m_a : m_b;
      float alk = cond ? ac_cl : gk;
      ml[k] = m; sw[k] = cond ? 0 : 1;
      al[k] = alk; ral[k] = __builtin_amdgcn_rcpf(alk);
      bu[k] = cond ? b_cur : a_nx;
      du[k] = cond ? 0.f : e_nx;
      float a_n = cond ? fmaf(-m, b_cur, a_nx) : fmaf(-m, a_nx, b_cur);
      float b_n = cond ? e_nx : (-m * e_nx);
      a_cur = a_n; b_cur = b_n;
    }
    if (fabsf(a_cur) < PIVMIN) a_cur = (a_cur >= 0.f) ? PIVMIN : -PIVMIN;
    al[127] = a_cur; ral[127] = __builtin_amdgcn_rcpf(a_cur);
  }
  __syncthreads();
  for (int pass = 0; pass < 2; ++pass) {
    if (tid == 0) {
      float yc = y[0];
      #pragma unroll 4
      for (int k = 0; k < 127; ++k) {
        float yn = y[k + 1];
        int t_ = sw[k];
        float ycs = t_ ? yn : yc;
        float yns = t_ ? yc : yn;
        y[k] = ycs;
        yc = fmaf(-ml[k], ycs, yns);
      }
      float y2 = yc * ral[127];
      float y1 = (y[126] - bu[126] * y2) * ral[126];
      y[127] = y2; y[126] = y1;
      #pragma unroll 4
      for (int k = 125; k >= 0; --k) {
        float yk = (y[k] - bu[k] * y1 - du[k] * y2) * ral[k];
        y[k] = yk;
        y2 = y1; y1 = yk;
      }
    }
    __syncthreads();
    float mx = 0.f;
    for (int t = tid; t < 128; t += 64) mx = fmaxf(mx, fabsf(y[t]));
    #pragma unroll
    for (int o = 32; o > 0; o >>= 1) mx = fmaxf(mx, __shfl_down(mx, o));
    mx = __shfl(mx, 0);
    float scl = 1.f / (mx + 1e-38f);
    for (int t = tid; t < 128; t += 64) y[t] *= scl;
    __syncthreads();
  }
  float nn = 0.f;
  for (int t = tid; t < 128; t += 64) { float v = y[t]; nn += v * v; }
  #pragma unroll
  for (int o = 32; o > 0; o >>= 1) nn += __shfl_down(nn, o);
  nn = __shfl(nn, 0);
  float inv = rsqrtf(nn + 1e-38f);
  for (int t = tid; t < 128; t += 64) Vtri[t * 128 + b] = y[t] * inv;
}

// ---------------- cluster Gram-Schmidt safety net (tol 1e-4, r14 green) -----
__global__ __launch_bounds__(128) void k_vfix(const float* __restrict__ lamb,
                                              float* __restrict__ Vtri) {
  __shared__ float lam_s[128];
  __shared__ float red[2];
  __shared__ unsigned long long msk[2];
  __shared__ int csh;
  int tid = threadIdx.x;
  lam_s[tid] = lamb[tid];
  __syncthreads();
  bool small = false;
  if (tid >= 1) {
    float gap = lam_s[tid] - lam_s[tid - 1];
    float tol = 1e-4f * fmaxf(1.f, fabsf(lam_s[tid]));
    small = gap < tol;
  }
  unsigned long long bw = __ballot(small);
  if ((tid & 63) == 0) msk[tid >> 6] = bw;
  __syncthreads();
  if (msk[0] == 0ULL && msk[1] == 0ULL) return;   // common case: no clusters
  if (tid == 0) csh = 0;
  __syncthreads();
  for (int i = 1; i < 128; ++i) {
    float gap = lam_s[i] - lam_s[i - 1];
    float tol = 1e-4f * fmaxf(1.f, fabsf(lam_s[i]));
    bool inclust = gap < tol;           // uniform across block
    if (!inclust) {
      if (tid == 0) csh = i;
      __syncthreads();
      continue;
    }
    __syncthreads();
    int cs = csh;
    for (int j = cs; j < i; ++j) {
      float vi = Vtri[tid * 128 + i];
      float vj = Vtri[tid * 128 + j];
      float p = vi * vj;
      #pragma unroll
      for (int o = 32; o > 0; o >>= 1) p += __shfl_down(p, o);
      if ((tid & 63) == 0) red[tid >> 6] = p;
      __syncthreads();
      float dt = red[0] + red[1];
      Vtri[tid * 128 + i] = vi - dt * vj;
      __syncthreads();
    }
    float vi = Vtri[tid * 128 + i];
    float p = vi * vi;
    #pragma unroll
    for (int o = 32; o > 0; o >>= 1) p += __shfl_down(p, o);
    if ((tid & 63) == 0) red[tid >> 6] = p;
    __syncthreads();
    Vtri[tid * 128 + i] = vi * rsqrtf(red[0] + red[1] + 1e-30f);
    __syncthreads();
  }
}

// ---------------- PT <- Q^T PT : barrier-free, register double-buffer -------
__global__ __launch_bounds__(128) void k_qtp(const float* __restrict__ vh,
                                             const float* __restrict__ betag,
                                             float* __restrict__ PT) {
  __shared__ float bsh[128];
  int tid = threadIdx.x;                 // 128
  int row = blockIdx.x * 16 + (tid >> 3);
  int part = tid & 7;
  for (int t = tid; t < 128; t += 128) bsh[t] = betag[t];
  float4 rv[4];
  const int rowoff = row * 128 + part * 16;
  #pragma unroll
  for (int t = 0; t < 4; ++t) rv[t] = *(const float4*)&PT[rowoff + t * 4];
  __syncthreads();                       // bsh ready; only barrier
  const int voff = part * 16;
  float4 nx0 = *(const float4*)&vh[voff + 0];
  float4 nx1 = *(const float4*)&vh[voff + 4];
  float4 nx2 = *(const float4*)&vh[voff + 8];
  float4 nx3 = *(const float4*)&vh[voff + 12];
  for (int k = 0; k < 126; ++k) {
    float4 c0 = nx0, c1 = nx1, c2 = nx2, c3 = nx3;
    if (k < 125) {
      const float* vp = &vh[(k + 1) * 128 + voff];
      nx0 = *(const float4*)&vp[0];
      nx1 = *(const float4*)&vp[4];
      nx2 = *(const float4*)&vp[8];
      nx3 = *(const float4*)&vp[12];
    }
    float dot = rv[0].x*c0.x + rv[0].y*c0.y + rv[0].z*c0.z + rv[0].w*c0.w
              + rv[1].x*c1.x + rv[1].y*c1.y + rv[1].z*c1.z + rv[1].w*c1.w
              + rv[2].x*c2.x + rv[2].y*c2.y + rv[2].z*c2.z + rv[2].w*c2.w
              + rv[3].x*c3.x + rv[3].y*c3.y + rv[3].z*c3.z + rv[3].w*c3.w;
    dot += __shfl_xor(dot, 1);
    dot += __shfl_xor(dot, 2);
    dot += __shfl_xor(dot, 4);
    float wk = bsh[k] * dot;
    rv[0].x -= wk*c0.x; rv[0].y -= wk*c0.y; rv[0].z -= wk*c0.z; rv[0].w -= wk*c0.w;
    rv[1].x -= wk*c1.x; rv[1].y -= wk*c1.y; rv[1].z -= wk*c1.z; rv[1].w -= wk*c1.w;
    rv[2].x -= wk*c2.x; rv[2].y -= wk*c2.y; rv[2].z -= wk*c2.z; rv[2].w -= wk*c2.w;
    rv[3].x -= wk*c3.x; rv[3].y -= wk*c3.y; rv[3].z -= wk*c3.z; rv[3].w -= wk*c3.w;
  }
  #pragma unroll
  for (int t = 0; t < 4; ++t) *(float4*)&PT[rowoff + t * 4] = rv[t];
}

// ---------------- per-sample stats (V = Vtri, p already Q^T-rotated) --------
__global__ void k_y_stats(const float* __restrict__ PT, const float* __restrict__ V,
                          const float* __restrict__ lam, const float* __restrict__ q1,
                          const float* __restrict__ nu_p, float* __restrict__ U,
                          float* __restrict__ bv, float* __restrict__ lv) {
  __shared__ float prow[RANK_];
  __shared__ float sbuf[2];
  int n = blockIdx.x, tid = threadIdx.x;  // 128
  prow[tid] = PT[n * RANK_ + tid];
  __syncthreads();
  float y = 0.f;
  for (int j = 0; j < RANK_; ++j) y += prow[j] * V[j * RANK_ + tid];
  float lamr = lam[tid];
  float s2 = y * y / lamr;
  float tot = blockReduceSum128(s2, sbuf);
  float q = q1[n] - tot;
  // exact-math invariant: q = x^T G x >= 0 (G PSD). Clamp makes the entire
  // downstream NaN-free (b>0 -> den=1+b*lam>1) regardless of eig quality.
  q = fmaxf(q, 0.f);
  float nuv = nu_p[0];
  float b = (nuv + (float)(D_DIM - RANK_)) / (nuv + q);
  float u = b * y;
  U[n * RANK_ + tid] = u;
  float den = 1.f + b * lamr;
  float part = u * u / den - logf(den);
  float l2 = blockReduceSum128(part, sbuf);
  if (tid == 0) { bv[n] = b; lv[n] = 0.5f * l2; }
}

// ---------------- pairwise score ----------------
__global__ __launch_bounds__(256) void k_score(const float* __restrict__ U,
                                               const float* __restrict__ bv,
                                               const float* __restrict__ lv,
                                               const float* __restrict__ lam,
                                               float* __restrict__ S) {
  __shared__ float Uts[128][68];
  __shared__ float Ues[128][36];
  __shared__ float lam_s[128];
  __shared__ float bt_s[64], lt_s[64], be_s[32], le_s[32];
  int tid = threadIdx.x;
  int e0 = blockIdx.x * 32, t0 = blockIdx.y * 64;
  int tx = tid & 15, ty = tid >> 4;
  #pragma unroll
  for (int l = 0; l < 8; ++l) {
    int idx = tid + l * 256;
    int row = idx >> 5, r4 = (idx & 31) << 2;
    float4 v = *(const float4*)&U[(t0 + row) * RANK_ + r4];
    Uts[r4+0][row] = v.x; Uts[r4+1][row] = v.y;
    Uts[r4+2][row] = v.z; Uts[r4+3][row] = v.w;
  }
  #pragma unroll
  for (int l = 0; l < 4; ++l) {
    int idx = tid + l * 256;
    int row = idx >> 5, r4 = (idx & 31) << 2;
    float4 v = *(const float4*)&U[(e0 + row) * RANK_ + r4];
    Ues[r4+0][row] = v.x; Ues[r4+1][row] = v.y;
    Ues[r4+2][row] = v.z; Ues[r4+3][row] = v.w;
  }
  if (tid < 128) lam_s[tid] = lam[tid];
  if (tid < 64) { bt_s[tid] = bv[t0 + tid]; lt_s[tid] = lv[t0 + tid]; }
  if (tid < 32) { be_s[tid] = bv[e0 + tid]; le_s[tid] = lv[e0 + tid]; }
  __syncthreads();

  float bt[4], lt[4], be[2], le[2];
  #pragma unroll
  for (int i = 0; i < 4; ++i) { bt[i] = bt_s[ty*4+i]; lt[i] = lt_s[ty*4+i]; }
  #pragma unroll
  for (int j = 0; j < 2; ++j) { be[j] = be_s[tx*2+j]; le[j] = le_s[tx*2+j]; }
  float bs[4][2], acc[4][2], pr[4][2], lg[4][2];
  #pragma unroll
  for (int i = 0; i < 4; ++i)
    #pragma unroll
    for (int j = 0; j < 2; ++j) {
      bs[i][j] = bt[i] + be[j];
      acc[i][j] = 0.f; pr[i][j] = 1.f; lg[i][j] = 0.f;
    }

  for (int r = 0; r < 128; ++r) {
    float lamr = lam_s[r];
    float4 utv = *(float4*)&Uts[r][ty * 4];
    float2 uev = *(float2*)&Ues[r][tx * 2];
    float ut[4] = {utv.x, utv.y, utv.z, utv.w};
    float ue[2] = {uev.x, uev.y};
    #pragma unroll
    for (int i = 0; i < 4; ++i)
      #pragma unroll
      for (int j = 0; j < 2; ++j) {
        float us = ut[i] + ue[j];
        float den = fmaf(bs[i][j], lamr, 1.f);
        float rc = __builtin_amdgcn_rcpf(den);
        acc[i][j] = fmaf(us * us, rc, acc[i][j]);
        pr[i][j] *= den;
      }
    if ((r & 7) == 7) {
      #pragma unroll
      for (int i = 0; i < 4; ++i)
        #pragma unroll
        for (int j = 0; j < 2; ++j) {
          lg[i][j] += __log2f(pr[i][j]);
          pr[i][j] = 1.f;
        }
    }
  }
  const float HL2 = 0.34657359027997264f;  // 0.5*ln(2)
  #pragma unroll
  for (int i = 0; i < 4; ++i) {
    int t = t0 + ty * 4 + i;
    float2 o;
    o.x = 0.5f * acc[i][0] - HL2 * lg[i][0] - lt[i] - le[0];
    o.y = 0.5f * acc[i][1] - HL2 * lg[i][1] - lt[i] - le[1];
    *(float2*)&S[t * NPTS + e0 + tx * 2] = o;
  }
}

// ---------------- launch ----------------
extern "C" void kernel_launch(void* const* d_in, const int* in_sizes, int n_in,
                              void* d_out, int out_size, void* d_ws, size_t ws_size,
                              hipStream_t stream) {
  const float* x  = (const float*)d_in[0];
  const float* H  = (const float*)d_in[1];
  const float* F  = (const float*)d_in[2];
  const float* mu = (const float*)d_in[3];
  const float* nu = (const float*)d_in[4];
  float* S = (float*)d_out;
  float* w = (float*)d_ws;
  float* HF  = w;              // 512*128   = 65536
  float* cv  = w + 65536;      // 512
  float* B0  = w + 66048;      // 128*128   = 16384
  float* R1  = w + 82432;      // 1024*512  = 524288 (dead after k_pt)
  float* PT  = w + 606720;     // 1024*128  = 131072
  float* q1  = w + 737792;     // 1024
  float* lamb= w + 755200;     // 128
  float* U   = w + 755328;     // 1024*128  = 131072
  float* bv  = w + 886400;     // 1024
  float* lv  = w + 887424;     // 1024
  // overlay inside dead R1 region [82432, 606720):
  float* dg    = w + 82432;            // 128
  float* eg    = w + 82560;            // 128
  float* betag = w + 82688;            // 128
  float* vh    = w + 82816;            // 128*128 = 16384
  float* Vtri  = w + 99200;            // 128*128 = 16384 (ends 115584)

  k_hf<<<dim3(512), dim3(128), 0, stream>>>(H, F, mu, HF, cv);
  k_b0<<<dim3(128), dim3(128), 0, stream>>>(HF, B0);
  k_r1<<<dim3(32, 8), dim3(256), 0, stream>>>(x, H, cv, R1);
  k_pt<<<dim3(1024), dim3(128), 0, stream>>>(R1, HF, PT, q1);
  k_tridiag<<<dim3(1), dim3(512), 0, stream>>>(B0, dg, eg, vh, betag, lamb);
  k_invit<<<dim3(128), dim3(64), 0, stream>>>(dg, eg, lamb, Vtri);
  k_vfix<<<dim3(1), dim3(128), 0, stream>>>(lamb, Vtri);
  k_qtp<<<dim3(64), dim3(128), 0, stream>>>(vh, betag, PT);
  k_y_stats<<<dim3(1024), dim3(128), 0, stream>>>(PT, Vtri, lamb, q1, nu, U, bv, lv);
  k_score<<<dim3(32, 16), dim3(256), 0, stream>>>(U, bv, lv, lamb, S);
}

// Round 18
// 530.093 us; speedup vs baseline: 1.0701x; 1.0701x over previous
//
#include <hip/hip_runtime.h>
#include <math.h>

#define D_DIM 512
#define RANK_ 128
#define NPTS 1024
#define BIS_ITERS 10

// ---------------- helpers ----------------
__device__ __forceinline__ float blockReduceSum128(float v, float* sbuf) {
  #pragma unroll
  for (int off = 32; off > 0; off >>= 1) v += __shfl_down(v, off);
  int tid = threadIdx.x;
  if ((tid & 63) == 0) sbuf[tid >> 6] = v;
  __syncthreads();
  float r = sbuf[0] + sbuf[1];
  __syncthreads();
  return r;
}

// ---------------- HF = H @ F ; c[i] = H_row_i . mu ----------------
__global__ void k_hf(const float* __restrict__ H, const float* __restrict__ F,
                     const float* __restrict__ mu, float* __restrict__ HF,
                     float* __restrict__ cvec) {
  __shared__ float hrow[D_DIM];
  __shared__ float sbuf[2];
  int i = blockIdx.x;        // 0..511
  int tid = threadIdx.x;     // 128 threads
  for (int d = tid; d < D_DIM; d += 128) hrow[d] = H[i * D_DIM + d];
  __syncthreads();
  float part = 0.f;
  for (int d = tid; d < D_DIM; d += 128) part += hrow[d] * mu[d];
  float ci = blockReduceSum128(part, sbuf);
  if (tid == 0) cvec[i] = ci;
  float acc = 0.f;
  for (int d = 0; d < D_DIM; ++d) acc += hrow[d] * F[d * RANK_ + tid];
  HF[i * RANK_ + tid] = acc;
}

// ---------------- B0 = HF^T @ HF ----------------
__global__ void k_b0(const float* __restrict__ HF, float* __restrict__ B0) {
  __shared__ float col[D_DIM];
  int r1 = blockIdx.x;       // 0..127
  int tid = threadIdx.x;     // 128
  for (int i = tid; i < D_DIM; i += 128) col[i] = HF[i * RANK_ + r1];
  __syncthreads();
  float acc = 0.f;
  for (int i = 0; i < D_DIM; ++i) acc += col[i] * HF[i * RANK_ + tid];
  B0[r1 * RANK_ + tid] = acc;
}

// ---------------- R1[n][i] = sum_d x[n][d]*H[i][d] - c[i] ----------------
__global__ void k_r1(const float* __restrict__ x, const float* __restrict__ H,
                     const float* __restrict__ cvec, float* __restrict__ R1) {
  __shared__ float xs[32][33];
  __shared__ float hs[64][33];
  int tid = threadIdx.x;
  int n0 = blockIdx.x * 32, i0 = blockIdx.y * 64;
  int tx = tid & 15, ty = tid >> 4;
  float acc[2][4] = {{0.f,0.f,0.f,0.f},{0.f,0.f,0.f,0.f}};
  for (int k0 = 0; k0 < D_DIM; k0 += 32) {
    {
      int idx = tid;
      int r = idx >> 3, c4 = (idx & 7) << 2;
      float4 v = *(const float4*)&x[(n0 + r) * D_DIM + k0 + c4];
      xs[r][c4+0]=v.x; xs[r][c4+1]=v.y; xs[r][c4+2]=v.z; xs[r][c4+3]=v.w;
    }
    #pragma unroll
    for (int l = 0; l < 2; ++l) {
      int idx = tid + l * 256;
      int r = idx >> 3, c4 = (idx & 7) << 2;
      float4 v = *(const float4*)&H[(i0 + r) * D_DIM + k0 + c4];
      hs[r][c4+0]=v.x; hs[r][c4+1]=v.y; hs[r][c4+2]=v.z; hs[r][c4+3]=v.w;
    }
    __syncthreads();
    #pragma unroll
    for (int k = 0; k < 32; ++k) {
      float a0 = xs[ty*2+0][k], a1 = xs[ty*2+1][k];
      float b0 = hs[tx*4+0][k], b1 = hs[tx*4+1][k];
      float b2 = hs[tx*4+2][k], b3 = hs[tx*4+3][k];
      acc[0][0] = fmaf(a0,b0,acc[0][0]); acc[0][1] = fmaf(a0,b1,acc[0][1]);
      acc[0][2] = fmaf(a0,b2,acc[0][2]); acc[0][3] = fmaf(a0,b3,acc[0][3]);
      acc[1][0] = fmaf(a1,b0,acc[1][0]); acc[1][1] = fmaf(a1,b1,acc[1][1]);
      acc[1][2] = fmaf(a1,b2,acc[1][2]); acc[1][3] = fmaf(a1,b3,acc[1][3]);
    }
    __syncthreads();
  }
  #pragma unroll
  for (int ii = 0; ii < 2; ++ii)
    #pragma unroll
    for (int j = 0; j < 4; ++j)
      R1[(n0 + ty*2 + ii) * D_DIM + i0 + tx*4 + j] = acc[ii][j] - cvec[i0 + tx*4 + j];
}

// ---------------- PT = R1 @ HF ; q1[n] = |R1 row|^2 ----------------
__global__ void k_pt(const float* __restrict__ R1, const float* __restrict__ HF,
                     float* __restrict__ PT, float* __restrict__ q1) {
  __shared__ float row[D_DIM];
  __shared__ float sbuf[2];
  int n = blockIdx.x, tid = threadIdx.x;  // 128
  float part = 0.f;
  for (int i = tid; i < D_DIM; i += 128) {
    float v = R1[n * D_DIM + i];
    row[i] = v;
    part += v * v;
  }
  float q = blockReduceSum128(part, sbuf);
  if (tid == 0) q1[n] = q;
  float acc = 0.f;
  for (int i = 0; i < D_DIM; ++i) acc += row[i] * HF[i * RANK_ + tid];
  PT[n * RANK_ + tid] = acc;
}

// ---------------- Householder tridiagonalization (r8 structure, green-proven
// r13/r14/r16) + FUSED trisection tail (BIS_ITERS=10 is this round's single
// experimental variable; 16 was green in r16). lamb positivity-clamped. ------
__global__ __launch_bounds__(512, 1) void k_tridiag(const float* __restrict__ B0,
                                                    float* __restrict__ dg,
                                                    float* __restrict__ eg,
                                                    float* __restrict__ vh,
                                                    float* __restrict__ betag,
                                                    float* __restrict__ lamb) {
  __shared__ __align__(16) float As[128][132];
  __shared__ __align__(16) float vbuf[128];
  __shared__ __align__(16) float wraw[128];
  __shared__ float red1[2];
  __shared__ float red2[8];
  __shared__ float dsh[128], esh[128], besb[128];
  __shared__ float gred[4];
  int tid = threadIdx.x;     // 512
  int lane = tid & 63, wv = tid >> 6;
  int slot = tid >> 2, sid = tid & 3;
  for (int idx = tid; idx < 128 * 128; idx += 512) {
    int i = idx >> 7, j = idx & 127;
    As[i][j] = B0[idx];
  }
  __syncthreads();

  for (int k = 0; k < 126; ++k) {
    int base = k + 1;
    int cb0 = base & ~3;           // f4-aligned active column window [cb0,128)
    int nf4 = (128 - cb0) >> 2;
    int bc = base & 3;             // base component within first f4
    // ---- phase 1: raw x -> vbuf (zeros below base), partial sigma^2 ----
    float xv = 0.f, px = 0.f;
    if (tid < 128) {
      xv = (tid >= base) ? As[tid][k] : 0.f;
      vbuf[tid] = xv;
      px = xv * xv;
    }
    #pragma unroll
    for (int o = 32; o > 0; o >>= 1) px += __shfl_down(px, o);
    if (tid < 128 && lane == 0) red1[wv] = px;
    __syncthreads();                                     // barrier 1
    // ---- redundant scalar Householder params (all 512 threads) ----
    float s2 = red1[0] + red1[1];
    float x1 = vbuf[base];       // LDS broadcast (raw)
    float beta = 0.f, e_k = 0.f, v1 = 0.f;
    if (s2 > 0.f) {
      float sg = sqrtf(s2);
      float sgn = (x1 >= 0.f) ? 1.f : -1.f;
      v1 = x1 + sgn * sg;
      float vtv = s2 - x1 * x1 + v1 * v1;
      beta = 2.f / vtv;
      e_k = -sgn * sg;
    }
    if (tid == 0) {
      float dkk = As[k][k];
      dg[k] = dkk; eg[k] = e_k; betag[k] = beta;
      dsh[k] = dkk; esh[k] = e_k;
    }
    if (tid < 128) vh[k * 128 + tid] = (tid == base) ? v1 : xv;
    // zero stale wraw entries in [cb0, base): read by phase 4's f4 loads
    if (tid < 3 && cb0 + tid < base) wraw[cb0 + tid] = 0.f;
    // ---- phase 2: rowdot with patched-v f4 loads; fused S reduce ----
    int j = base + slot;
    const int rowbase = cb0;
    float sp = 0.f;
    {
      float part = 0.f;
      if (j < 128) {
        const float* arow = &As[j][0];
        for (int t4 = sid; t4 < nf4; t4 += 4) {
          float4 a = *(const float4*)&arow[rowbase + 4 * t4];
          float4 v = *(const float4*)&vbuf[rowbase + 4 * t4];
          if (t4 == 0) {           // f4 containing base: substitute v1
            v.x = (bc == 0) ? v1 : v.x;
            v.y = (bc == 1) ? v1 : v.y;
            v.z = (bc == 2) ? v1 : v.z;
            v.w = (bc == 3) ? v1 : v.w;
          }
          part += a.x * v.x + a.y * v.y + a.z * v.z + a.w * v.w;
        }
      }
      part += __shfl_xor(part, 1);
      part += __shfl_xor(part, 2);
      if (j < 128 && sid == 0) {
        wraw[j] = part;
        float vj = (j == base) ? v1 : vbuf[j];
        sp = vj * part;
      }
    }
    #pragma unroll
    for (int o = 32; o > 0; o >>= 1) sp += __shfl_down(sp, o);
    if (lane == 0) red2[wv] = sp;
    __syncthreads();                                     // barrier 2
    // ---- phase 4 (merged w/ 3): A -= v*w^T + w*v^T, w computed on the fly --
    float S = red2[0] + red2[1] + red2[2] + red2[3]
            + red2[4] + red2[5] + red2[6] + red2[7];
    float coef = 0.5f * beta * beta * S;
    if (j < 128) {
      float vj = (j == base) ? v1 : vbuf[j];
      float wj = beta * wraw[j] - coef * vj;
      float* arow = &As[j][0];
      for (int t4 = sid; t4 < nf4; t4 += 4) {
        float4* ap = (float4*)&arow[rowbase + 4 * t4];
        float4 v = *(const float4*)&vbuf[rowbase + 4 * t4];
        float4 wr = *(const float4*)&wraw[rowbase + 4 * t4];
        if (t4 == 0) {
          v.x = (bc == 0) ? v1 : v.x;
          v.y = (bc == 1) ? v1 : v.y;
          v.z = (bc == 2) ? v1 : v.z;
          v.w = (bc == 3) ? v1 : v.w;
        }
        float4 w4;
        w4.x = beta * wr.x - coef * v.x;
        w4.y = beta * wr.y - coef * v.y;
        w4.z = beta * wr.z - coef * v.z;
        w4.w = beta * wr.w - coef * v.w;
        float4 a = *ap;
        a.x -= vj * w4.x + wj * v.x;
        a.y -= vj * w4.y + wj * v.y;
        a.z -= vj * w4.z + wj * v.z;
        a.w -= vj * w4.w + wj * v.w;
        *ap = a;
      }
    }
    __syncthreads();                                     // barrier 3
  }
  if (tid == 0) {
    float d126 = As[126][126], d127 = As[127][127], e126 = As[127][126];
    dg[126] = d126; dg[127] = d127;
    eg[126] = e126; eg[127] = 0.f;
    betag[126] = 0.f; betag[127] = 0.f;
    dsh[126] = d126; dsh[127] = d127;
    esh[126] = e126; esh[127] = 0.f;
  }
  __syncthreads();

  // ================= fused trisection (pdv=vbuf, pev=wraw) ===================
  float* pdv = vbuf;
  float* pev = wraw;
  float dvv = 0.f;
  if (tid < 128) {
    dvv = dsh[tid];
    float ev = (tid < 127) ? esh[tid] : 0.f;
    pdv[tid] = dvv;
    besb[tid] = fabsf(ev);
  }
  __syncthreads();
  if (tid < 128) {
    float em1 = (tid > 0) ? besb[tid - 1] : 0.f;
    pev[tid] = em1 * em1;                  // pe[k] = e_{k-1}^2, pe[0]=0
    float rad = em1 + besb[tid];
    float lo_k = dvv - rad, hi_k = dvv + rad;
    #pragma unroll
    for (int o = 32; o > 0; o >>= 1) {
      lo_k = fminf(lo_k, __shfl_down(lo_k, o));
      hi_k = fmaxf(hi_k, __shfl_down(hi_k, o));
    }
    if (lane == 0) { gred[wv * 2] = lo_k; gred[wv * 2 + 1] = hi_k; }
  }
  __syncthreads();
  if (tid < 128) {
    float gl = fminf(gred[0], gred[2]), gu = fmaxf(gred[1], gred[3]);
    float span = gu - gl;
    gl -= 0.01f * span + 1e-3f;
    gu += 0.01f * span + 1e-3f;
    float lo = gl, hi = gu;
    const float PIVMIN = 1e-20f;
    for (int it = 0; it < BIS_ITERS; ++it) {
      float w3 = (hi - lo) * (1.f / 3.f);
      float m1 = lo + w3, m2 = hi - w3;
      int c1 = 0, c2 = 0;
      float q1 = 1.f, q2 = 1.f;
      #pragma unroll 1
      for (int kq = 0; kq < 32; ++kq) {
        float4 pd4 = *(const float4*)&pdv[kq * 4];
        float4 pe4 = *(const float4*)&pev[kq * 4];
        #pragma unroll
        for (int u = 0; u < 4; ++u) {
          float dk = (u == 0) ? pd4.x : (u == 1) ? pd4.y : (u == 2) ? pd4.z : pd4.w;
          float ee = (u == 0) ? pe4.x : (u == 1) ? pe4.y : (u == 2) ? pe4.z : pe4.w;
          if (fabsf(q1) < PIVMIN) q1 = -PIVMIN;
          if (fabsf(q2) < PIVMIN) q2 = -PIVMIN;
          q1 = (dk - m1) - ee * __builtin_amdgcn_rcpf(q1);
          q2 = (dk - m2) - ee * __builtin_amdgcn_rcpf(q2);
          c1 += (q1 < 0.f); c2 += (q2 < 0.f);
        }
      }
      if (c1 > tid)       hi = m1;
      else if (c2 > tid) { lo = m1; hi = m2; }
      else                lo = m2;
    }
    // positivity clamp: B0 is PD so exact lambda > 0; guarantees den=1+b*lam>1
    lamb[tid] = fmaxf(0.5f * (lo + hi), 1e-6f);
  }
}

// ---------------- inverse iteration: branchless pivoting, pipelined ---------
__global__ __launch_bounds__(64) void k_invit(const float* __restrict__ dg,
                                              const float* __restrict__ eg,
                                              const float* __restrict__ lamb,
                                              float* __restrict__ Vtri) {
  __shared__ float al[128], bu[128], du[128], ml[128], es[128], y[128];
  __shared__ float esp[128], alp[128], ral[128];
  __shared__ int sw[128];
  int b = blockIdx.x, tid = threadIdx.x;  // 64
  float lam = lamb[b];
  for (int t = tid; t < 128; t += 64) {
    float av = dg[t] - lam;
    al[t] = av;
    float e_ = (t < 127) ? eg[t] : 0.f;
    es[t] = e_;
    unsigned int h = (unsigned int)(t * 2654435761u) ^ (unsigned int)(b * 0x9E3779B9u);
    h ^= h >> 16; h *= 0x85EBCA6Bu; h ^= h >> 13;
    y[t] = 0.5f + (float)(h & 0xFFFF) * (1.0f / 65536.0f);
  }
  __syncthreads();
  for (int t = tid; t < 128; t += 64) {
    esp[t] = (t < 127) ? es[t + 1] : 0.f;
    alp[t] = (t < 127) ? al[t + 1] : 0.f;
  }
  __syncthreads();
  if (tid == 0) {
    const float PIVMIN = 1e-20f;
    float a_cur = al[0];
    float b_cur = es[0];
    #pragma unroll 4
    for (int k = 0; k < 127; ++k) {
      float gk = es[k], e_nx = esp[k], a_nx = alp[k];
      bool cond = fabsf(a_cur) >= fabsf(gk);
      float ac_cl = a_cur;
      if (fabsf(ac_cl) < PIVMIN) ac_cl = (ac_cl >= 0.f) ? PIVMIN : -PIVMIN;
      float m_a = gk * __builtin_amdgcn_rcpf(ac_cl);
      float m_b = a_cur * __builtin_amdgcn_rcpf(gk);
      float m = cond ? m_a : m_b;
      float alk = cond ? ac_cl : gk;
      ml[k] = m; sw[k] = cond ? 0 : 1;
      al[k] = alk; ral[k] = __builtin_amdgcn_rcpf(alk);
      bu[k] = cond ? b_cur : a_nx;
      du[k] = cond ? 0.f : e_nx;
      float a_n = cond ? fmaf(-m, b_cur, a_nx) : fmaf(-m, a_nx, b_cur);
      float b_n = cond ? e_nx : (-m * e_nx);
      a_cur = a_n; b_cur = b_n;
    }
    if (fabsf(a_cur) < PIVMIN) a_cur = (a_cur >= 0.f) ? PIVMIN : -PIVMIN;
    al[127] = a_cur; ral[127] = __builtin_amdgcn_rcpf(a_cur);
  }
  __syncthreads();
  for (int pass = 0; pass < 2; ++pass) {
    if (tid == 0) {
      float yc = y[0];
      #pragma unroll 4
      for (int k = 0; k < 127; ++k) {
        float yn = y[k + 1];
        int t_ = sw[k];
        float ycs = t_ ? yn : yc;
        float yns = t_ ? yc : yn;
        y[k] = ycs;
        yc = fmaf(-ml[k], ycs, yns);
      }
      float y2 = yc * ral[127];
      float y1 = (y[126] - bu[126] * y2) * ral[126];
      y[127] = y2; y[126] = y1;
      #pragma unroll 4
      for (int k = 125; k >= 0; --k) {
        float yk = (y[k] - bu[k] * y1 - du[k] * y2) * ral[k];
        y[k] = yk;
        y2 = y1; y1 = yk;
      }
    }
    __syncthreads();
    float mx = 0.f;
    for (int t = tid; t < 128; t += 64) mx = fmaxf(mx, fabsf(y[t]));
    #pragma unroll
    for (int o = 32; o > 0; o >>= 1) mx = fmaxf(mx, __shfl_down(mx, o));
    mx = __shfl(mx, 0);
    float scl = 1.f / (mx + 1e-38f);
    for (int t = tid; t < 128; t += 64) y[t] *= scl;
    __syncthreads();
  }
  float nn = 0.f;
  for (int t = tid; t < 128; t += 64) { float v = y[t]; nn += v * v; }
  #pragma unroll
  for (int o = 32; o > 0; o >>= 1) nn += __shfl_down(nn, o);
  nn = __shfl(nn, 0);
  float inv = rsqrtf(nn + 1e-38f);
  for (int t = tid; t < 128; t += 64) Vtri[t * 128 + b] = y[t] * inv;
}

// ---------------- cluster Gram-Schmidt safety net (tol 1e-4, r14 green) -----
__global__ __launch_bounds__(128) void k_vfix(const float* __restrict__ lamb,
                                              float* __restrict__ Vtri) {
  __shared__ float lam_s[128];
  __shared__ float red[2];
  __shared__ unsigned long long msk[2];
  __shared__ int csh;
  int tid = threadIdx.x;
  lam_s[tid] = lamb[tid];
  __syncthreads();
  bool small = false;
  if (tid >= 1) {
    float gap = lam_s[tid] - lam_s[tid - 1];
    float tol = 1e-4f * fmaxf(1.f, fabsf(lam_s[tid]));
    small = gap < tol;
  }
  unsigned long long bw = __ballot(small);
  if ((tid & 63) == 0) msk[tid >> 6] = bw;
  __syncthreads();
  if (msk[0] == 0ULL && msk[1] == 0ULL) return;   // common case: no clusters
  if (tid == 0) csh = 0;
  __syncthreads();
  for (int i = 1; i < 128; ++i) {
    float gap = lam_s[i] - lam_s[i - 1];
    float tol = 1e-4f * fmaxf(1.f, fabsf(lam_s[i]));
    bool inclust = gap < tol;           // uniform across block
    if (!inclust) {
      if (tid == 0) csh = i;
      __syncthreads();
      continue;
    }
    __syncthreads();
    int cs = csh;
    for (int j = cs; j < i; ++j) {
      float vi = Vtri[tid * 128 + i];
      float vj = Vtri[tid * 128 + j];
      float p = vi * vj;
      #pragma unroll
      for (int o = 32; o > 0; o >>= 1) p += __shfl_down(p, o);
      if ((tid & 63) == 0) red[tid >> 6] = p;
      __syncthreads();
      float dt = red[0] + red[1];
      Vtri[tid * 128 + i] = vi - dt * vj;
      __syncthreads();
    }
    float vi = Vtri[tid * 128 + i];
    float p = vi * vi;
    #pragma unroll
    for (int o = 32; o > 0; o >>= 1) p += __shfl_down(p, o);
    if ((tid & 63) == 0) red[tid >> 6] = p;
    __syncthreads();
    Vtri[tid * 128 + i] = vi * rsqrtf(red[0] + red[1] + 1e-30f);
    __syncthreads();
  }
}

// ---------------- PT <- Q^T PT : barrier-free, register double-buffer -------
__global__ __launch_bounds__(128) void k_qtp(const float* __restrict__ vh,
                                             const float* __restrict__ betag,
                                             float* __restrict__ PT) {
  __shared__ float bsh[128];
  int tid = threadIdx.x;                 // 128
  int row = blockIdx.x * 16 + (tid >> 3);
  int part = tid & 7;
  for (int t = tid; t < 128; t += 128) bsh[t] = betag[t];
  float4 rv[4];
  const int rowoff = row * 128 + part * 16;
  #pragma unroll
  for (int t = 0; t < 4; ++t) rv[t] = *(const float4*)&PT[rowoff + t * 4];
  __syncthreads();                       // bsh ready; only barrier
  const int voff = part * 16;
  float4 nx0 = *(const float4*)&vh[voff + 0];
  float4 nx1 = *(const float4*)&vh[voff + 4];
  float4 nx2 = *(const float4*)&vh[voff + 8];
  float4 nx3 = *(const float4*)&vh[voff + 12];
  for (int k = 0; k < 126; ++k) {
    float4 c0 = nx0, c1 = nx1, c2 = nx2, c3 = nx3;
    if (k < 125) {
      const float* vp = &vh[(k + 1) * 128 + voff];
      nx0 = *(const float4*)&vp[0];
      nx1 = *(const float4*)&vp[4];
      nx2 = *(const float4*)&vp[8];
      nx3 = *(const float4*)&vp[12];
    }
    float dot = rv[0].x*c0.x + rv[0].y*c0.y + rv[0].z*c0.z + rv[0].w*c0.w
              + rv[1].x*c1.x + rv[1].y*c1.y + rv[1].z*c1.z + rv[1].w*c1.w
              + rv[2].x*c2.x + rv[2].y*c2.y + rv[2].z*c2.z + rv[2].w*c2.w
              + rv[3].x*c3.x + rv[3].y*c3.y + rv[3].z*c3.z + rv[3].w*c3.w;
    dot += __shfl_xor(dot, 1);
    dot += __shfl_xor(dot, 2);
    dot += __shfl_xor(dot, 4);
    float wk = bsh[k] * dot;
    rv[0].x -= wk*c0.x; rv[0].y -= wk*c0.y; rv[0].z -= wk*c0.z; rv[0].w -= wk*c0.w;
    rv[1].x -= wk*c1.x; rv[1].y -= wk*c1.y; rv[1].z -= wk*c1.z; rv[1].w -= wk*c1.w;
    rv[2].x -= wk*c2.x; rv[2].y -= wk*c2.y; rv[2].z -= wk*c2.z; rv[2].w -= wk*c2.w;
    rv[3].x -= wk*c3.x; rv[3].y -= wk*c3.y; rv[3].z -= wk*c3.z; rv[3].w -= wk*c3.w;
  }
  #pragma unroll
  for (int t = 0; t < 4; ++t) *(float4*)&PT[rowoff + t * 4] = rv[t];
}

// ---------------- per-sample stats (V = Vtri, p already Q^T-rotated) --------
__global__ void k_y_stats(const float* __restrict__ PT, const float* __restrict__ V,
                          const float* __restrict__ lam, const float* __restrict__ q1,
                          const float* __restrict__ nu_p, float* __restrict__ U,
                          float* __restrict__ bv, float* __restrict__ lv) {
  __shared__ float prow[RANK_];
  __shared__ float sbuf[2];
  int n = blockIdx.x, tid = threadIdx.x;  // 128
  prow[tid] = PT[n * RANK_ + tid];
  __syncthreads();
  float y = 0.f;
  for (int j = 0; j < RANK_; ++j) y += prow[j] * V[j * RANK_ + tid];
  float lamr = lam[tid];
  float s2 = y * y / lamr;
  float tot = blockReduceSum128(s2, sbuf);
  float q = q1[n] - tot;
  // exact-math invariant: q = x^T G x >= 0 (G PSD). Clamp makes the entire
  // downstream NaN-free (b>0 -> den=1+b*lam>1) regardless of eig quality.
  q = fmaxf(q, 0.f);
  float nuv = nu_p[0];
  float b = (nuv + (float)(D_DIM - RANK_)) / (nuv + q);
  float u = b * y;
  U[n * RANK_ + tid] = u;
  float den = 1.f + b * lamr;
  float part = u * u / den - logf(den);
  float l2 = blockReduceSum128(part, sbuf);
  if (tid == 0) { bv[n] = b; lv[n] = 0.5f * l2; }
}

// ---------------- pairwise score ----------------
__global__ __launch_bounds__(256) void k_score(const float* __restrict__ U,
                                               const float* __restrict__ bv,
                                               const float* __restrict__ lv,
                                               const float* __restrict__ lam,
                                               float* __restrict__ S) {
  __shared__ float Uts[128][68];
  __shared__ float Ues[128][36];
  __shared__ float lam_s[128];
  __shared__ float bt_s[64], lt_s[64], be_s[32], le_s[32];
  int tid = threadIdx.x;
  int e0 = blockIdx.x * 32, t0 = blockIdx.y * 64;
  int tx = tid & 15, ty = tid >> 4;
  #pragma unroll
  for (int l = 0; l < 8; ++l) {
    int idx = tid + l * 256;
    int row = idx >> 5, r4 = (idx & 31) << 2;
    float4 v = *(const float4*)&U[(t0 + row) * RANK_ + r4];
    Uts[r4+0][row] = v.x; Uts[r4+1][row] = v.y;
    Uts[r4+2][row] = v.z; Uts[r4+3][row] = v.w;
  }
  #pragma unroll
  for (int l = 0; l < 4; ++l) {
    int idx = tid + l * 256;
    int row = idx >> 5, r4 = (idx & 31) << 2;
    float4 v = *(const float4*)&U[(e0 + row) * RANK_ + r4];
    Ues[r4+0][row] = v.x; Ues[r4+1][row] = v.y;
    Ues[r4+2][row] = v.z; Ues[r4+3][row] = v.w;
  }
  if (tid < 128) lam_s[tid] = lam[tid];
  if (tid < 64) { bt_s[tid] = bv[t0 + tid]; lt_s[tid] = lv[t0 + tid]; }
  if (tid < 32) { be_s[tid] = bv[e0 + tid]; le_s[tid] = lv[e0 + tid]; }
  __syncthreads();

  float bt[4], lt[4], be[2], le[2];
  #pragma unroll
  for (int i = 0; i < 4; ++i) { bt[i] = bt_s[ty*4+i]; lt[i] = lt_s[ty*4+i]; }
  #pragma unroll
  for (int j = 0; j < 2; ++j) { be[j] = be_s[tx*2+j]; le[j] = le_s[tx*2+j]; }
  float bs[4][2], acc[4][2], pr[4][2], lg[4][2];
  #pragma unroll
  for (int i = 0; i < 4; ++i)
    #pragma unroll
    for (int j = 0; j < 2; ++j) {
      bs[i][j] = bt[i] + be[j];
      acc[i][j] = 0.f; pr[i][j] = 1.f; lg[i][j] = 0.f;
    }

  for (int r = 0; r < 128; ++r) {
    float lamr = lam_s[r];
    float4 utv = *(float4*)&Uts[r][ty * 4];
    float2 uev = *(float2*)&Ues[r][tx * 2];
    float ut[4] = {utv.x, utv.y, utv.z, utv.w};
    float ue[2] = {uev.x, uev.y};
    #pragma unroll
    for (int i = 0; i < 4; ++i)
      #pragma unroll
      for (int j = 0; j < 2; ++j) {
        float us = ut[i] + ue[j];
        float den = fmaf(bs[i][j], lamr, 1.f);
        float rc = __builtin_amdgcn_rcpf(den);
        acc[i][j] = fmaf(us * us, rc, acc[i][j]);
        pr[i][j] *= den;
      }
    if ((r & 7) == 7) {
      #pragma unroll
      for (int i = 0; i < 4; ++i)
        #pragma unroll
        for (int j = 0; j < 2; ++j) {
          lg[i][j] += __log2f(pr[i][j]);
          pr[i][j] = 1.f;
        }
    }
  }
  const float HL2 = 0.34657359027997264f;  // 0.5*ln(2)
  #pragma unroll
  for (int i = 0; i < 4; ++i) {
    int t = t0 + ty * 4 + i;
    float2 o;
    o.x = 0.5f * acc[i][0] - HL2 * lg[i][0] - lt[i] - le[0];
    o.y = 0.5f * acc[i][1] - HL2 * lg[i][1] - lt[i] - le[1];
    *(float2*)&S[t * NPTS + e0 + tx * 2] = o;
  }
}

// ---------------- launch ----------------
extern "C" void kernel_launch(void* const* d_in, const int* in_sizes, int n_in,
                              void* d_out, int out_size, void* d_ws, size_t ws_size,
                              hipStream_t stream) {
  const float* x  = (const float*)d_in[0];
  const float* H  = (const float*)d_in[1];
  const float* F  = (const float*)d_in[2];
  const float* mu = (const float*)d_in[3];
  const float* nu = (const float*)d_in[4];
  float* S = (float*)d_out;
  float* w = (float*)d_ws;
  float* HF  = w;              // 512*128   = 65536
  float* cv  = w + 65536;      // 512
  float* B0  = w + 66048;      // 128*128   = 16384
  float* R1  = w + 82432;      // 1024*512  = 524288 (dead after k_pt)
  float* PT  = w + 606720;     // 1024*128  = 131072
  float* q1  = w + 737792;     // 1024
  float* lamb= w + 755200;     // 128
  float* U   = w + 755328;     // 1024*128  = 131072
  float* bv  = w + 886400;     // 1024
  float* lv  = w + 887424;     // 1024
  // overlay inside dead R1 region [82432, 606720):
  float* dg    = w + 82432;            // 128
  float* eg    = w + 82560;            // 128
  float* betag = w + 82688;            // 128
  float* vh    = w + 82816;            // 128*128 = 16384
  float* Vtri  = w + 99200;            // 128*128 = 16384 (ends 115584)

  k_hf<<<dim3(512), dim3(128), 0, stream>>>(H, F, mu, HF, cv);
  k_b0<<<dim3(128), dim3(128), 0, stream>>>(HF, B0);
  k_r1<<<dim3(32, 8), dim3(256), 0, stream>>>(x, H, cv, R1);
  k_pt<<<dim3(1024), dim3(128), 0, stream>>>(R1, HF, PT, q1);
  k_tridiag<<<dim3(1), dim3(512), 0, stream>>>(B0, dg, eg, vh, betag, lamb);
  k_invit<<<dim3(128), dim3(64), 0, stream>>>(dg, eg, lamb, Vtri);
  k_vfix<<<dim3(1), dim3(128), 0, stream>>>(lamb, Vtri);
  k_qtp<<<dim3(64), dim3(128), 0, stream>>>(vh, betag, PT);
  k_y_stats<<<dim3(1024), dim3(128), 0, stream>>>(PT, Vtri, lamb, q1, nu, U, bv, lv);
  k_score<<<dim3(32, 16), dim3(256), 0, stream>>>(U, bv, lv, lamb, S);
}